// Round 13
// baseline (523.454 us; speedup 1.0000x reference)
//
#include <hip/hip_runtime.h>
#include <hip/hip_fp16.h>
#include <math.h>

#define N_NODES 50000
#define N_EDGES 800000
#define ATOMF 64
#define DIN 192
#define DOUT 128
#define EPB 64
#define NTILES (N_EDGES / EPB)   // 12500
#define LDW 200                  // fallback LDS stride
#define ZLD 136                  // z-LDS row stride in fp16 (272B, 16B-aligned rows)

typedef __attribute__((ext_vector_type(8))) short bf16x8;
typedef __attribute__((ext_vector_type(8))) short s16x8;
typedef __attribute__((ext_vector_type(4))) float f32x4;

__device__ __forceinline__ short f2bf(float f) {
  unsigned u = __float_as_uint(f);
  u += 0x7fffu + ((u >> 16) & 1u);   // RNE
  return (short)(u >> 16);
}
__device__ __forceinline__ unsigned short f2h(float f) {
  __half h = __float2half_rn(f);     // v_cvt_f16_f32 (RNE)
  return *(unsigned short*)&h;
}
__device__ __forceinline__ float h2f(unsigned short u) {
  __half h = *(__half*)&u;
  return __half2float(h);            // v_cvt_f32_f16
}
__device__ __forceinline__ float softplus_f(float x) {
  return fmaxf(x, 0.f) + log1pf(__expf(-fabsf(x)));
}
__device__ __forceinline__ float sigmoid_f(float x) {
  return 1.f / (1.f + __expf(-x));
}
// fast variants for the 51.2M-element gate (err ~1e-6, threshold 0.24)
__device__ __forceinline__ float fast_sigmoid(float x) {
  return __builtin_amdgcn_rcpf(1.f + __expf(-x));
}
__device__ __forceinline__ float fast_softplus(float x) {
  return fmaxf(x, 0.f) + __logf(1.f + __expf(-fabsf(x)));
}

// ---------------- fp32 -> bf16 pre-convert + fused degree histogram ----------
__launch_bounds__(256)
__global__ void precvt_k(const float* __restrict__ atom,
                         const float* __restrict__ nbr,
                         const int* __restrict__ edst,
                         unsigned short* __restrict__ atom_bf,
                         unsigned short* __restrict__ nbr_bf,
                         int* __restrict__ deg) {
  const int NA = N_NODES * ATOMF / 8;        // 400000 chunks of 8
  const int NB = N_EDGES * ATOMF / 8;        // 6400000
  int gid = blockIdx.x * blockDim.x + threadIdx.x;
  int stride = gridDim.x * blockDim.x;
  if (deg) {   // fused histogram: 800k L2 atomics hide under the stream
    for (int i = gid; i < N_EDGES; i += stride) atomicAdd(&deg[edst[i]], 1);
  }
  for (int i = gid; i < NA + NB; i += stride) {
    const float* s;
    unsigned short* d;
    if (i < NA) { s = atom + (size_t)i * 8; d = atom_bf + (size_t)i * 8; }
    else        { s = nbr + (size_t)(i - NA) * 8; d = nbr_bf + (size_t)(i - NA) * 8; }
    float4 a = ((const float4*)s)[0];
    float4 b = ((const float4*)s)[1];
    s16x8 t;
    t[0] = f2bf(a.x); t[1] = f2bf(a.y); t[2] = f2bf(a.z); t[3] = f2bf(a.w);
    t[4] = f2bf(b.x); t[5] = f2bf(b.y); t[6] = f2bf(b.z); t[7] = f2bf(b.w);
    *(s16x8*)d = t;
  }
}

// ---------------- CSR build: scan (x4 vectorized) -> fill (inverse perm) -----
__launch_bounds__(1024)
__global__ void scan_k(const int* __restrict__ deg,
                       int* __restrict__ rowptr,
                       int* __restrict__ cursor) {
  __shared__ int wsum[16];
  const int tid = threadIdx.x;
  const int lane = tid & 63, wv = tid >> 6;
  const int N4 = N_NODES / 4;                // 12500 int4 chunks
  int base = 0;
  for (int c0 = 0; c0 < N4; c0 += 1024) {
    int i4 = c0 + tid;
    int4 v = make_int4(0, 0, 0, 0);
    if (i4 < N4) v = ((const int4*)deg)[i4];
    int t = v.x + v.y + v.z + v.w;
    int s = t;
    #pragma unroll
    for (int d = 1; d < 64; d <<= 1) {
      int u = __shfl_up(s, d, 64);
      if (lane >= d) s += u;
    }
    if (lane == 63) wsum[wv] = s;
    __syncthreads();
    if (wv == 0 && lane < 16) {
      int ws = wsum[lane];
      #pragma unroll
      for (int d = 1; d < 16; d <<= 1) {
        int u = __shfl_up(ws, d, 64);
        if (lane >= d) ws += u;
      }
      wsum[lane] = ws;
    }
    __syncthreads();
    int wbase = wv ? wsum[wv - 1] : 0;
    int excl = base + wbase + s - t;         // exclusive prefix for 4-chunk
    if (i4 < N4) {
      int4 r;
      r.x = excl;
      r.y = excl + v.x;
      r.z = r.y + v.y;
      r.w = r.z + v.z;
      ((int4*)rowptr)[i4] = r;
      ((int4*)cursor)[i4] = r;
    }
    int tot = wsum[15];
    __syncthreads();   // everyone done reading wsum before next iter overwrites
    base += tot;
  }
  if (tid == 0) rowptr[N_NODES] = base;      // == N_EDGES
}

__launch_bounds__(256)
__global__ void fill_k(const int* __restrict__ edst,
                       int* __restrict__ cursor,
                       int* __restrict__ iperm) {
  int gid = blockIdx.x * 256 + threadIdx.x;
  if (gid < N_EDGES) {
    int pos = atomicAdd(&cursor[edst[gid]], 1);
    iperm[gid] = pos;          // inverse perm: edge -> CSR slot
  }
}

// ---------------- edge pass: DIRECT-LOAD fragments -> MFMA -> z rows ---------
// No LDS staging: each lane loads its 16B MFMA A-fragment straight from global
// (fragment cols kk*32+lg*8 never cross a 64-col source boundary; source
// select = kk>>1). Register-dest loads => normal compiler waitcnt/scheduling.
// LDS only for the z transpose (2 barriers/tile).
// Round-12 diagnosis: latency-bound at the launch_bounds occupancy cap (43%,
// nothing saturated). This round: (256,6) + grid 1536 = 6 blocks/CU resident
// (VGPR cap ~84 > 64 actual, LDS 6x17.4=104KB < 160KB).
// z_csr layout: zc[pos][128] fp16, row-major, pos = CSR slot of the edge.
__launch_bounds__(256, 6)
__global__ void edge_gemm(const unsigned short* __restrict__ atom_bf,
                          const unsigned short* __restrict__ nbr_bf,
                          const int* __restrict__ esrc,
                          const int* __restrict__ edst,
                          const int* __restrict__ iperm,
                          const float* __restrict__ W,
                          float* __restrict__ stats,
                          unsigned short* __restrict__ zc) {
  __shared__ unsigned short Zl[EPB * ZLD];   // 17408 B (z transpose only)

  const int tid = threadIdx.x;
  const int lane = tid & 63;
  const int wv = tid >> 6;
  const int l15 = lane & 15;
  const int lg = lane >> 4;
  const int colF = wv * 16 + l15;            // filter column
  const int colC = colF + 64;                // core column

  // W fragments in registers: wf[cg][kk][jj] = W[kk*32+lg*8+jj][cg*64+colF]
  bf16x8 wf[2][6];
  #pragma unroll
  for (int cg = 0; cg < 2; ++cg) {
    #pragma unroll
    for (int kk = 0; kk < 6; ++kk) {
      bf16x8 t;
      #pragma unroll
      for (int jj = 0; jj < 8; ++jj)
        t[jj] = f2bf(W[(size_t)(kk * 32 + lg * 8 + jj) * 128 + cg * 64 + colF]);
      wf[cg][kk] = t;
    }
  }

  const int orow = tid >> 2;                 // output row 0..63
  const int oq = tid & 3;                    // 32-col chunk 0..3

  float fs[2] = {0.f, 0.f}, fq[2] = {0.f, 0.f};

  for (int tile = blockIdx.x; tile < NTILES; tile += gridDim.x) {
    const int e0 = tile * EPB;

    f32x4 acc[2][4] = {};
    #pragma unroll
    for (int rg = 0; rg < 4; ++rg) {
      int e = e0 + rg * 16 + l15;            // this lane's edge row
      const unsigned short* srcb = atom_bf + (size_t)esrc[e] * ATOMF + lg * 8;
      const unsigned short* dstb = atom_bf + (size_t)edst[e] * ATOMF + lg * 8;
      const unsigned short* nbrb = nbr_bf + (size_t)e * ATOMF + lg * 8;
      bf16x8 a0 = *(const bf16x8*)srcb;        // cols   0.. 31 slice
      bf16x8 a1 = *(const bf16x8*)(srcb + 32); // cols  32.. 63
      bf16x8 a2 = *(const bf16x8*)dstb;        // cols  64.. 95
      bf16x8 a3 = *(const bf16x8*)(dstb + 32); // cols  96..127
      bf16x8 a4 = *(const bf16x8*)nbrb;        // cols 128..159
      bf16x8 a5 = *(const bf16x8*)(nbrb + 32); // cols 160..191
      acc[0][rg] = __builtin_amdgcn_mfma_f32_16x16x32_bf16(a0, wf[0][0], acc[0][rg], 0, 0, 0);
      acc[1][rg] = __builtin_amdgcn_mfma_f32_16x16x32_bf16(a0, wf[1][0], acc[1][rg], 0, 0, 0);
      acc[0][rg] = __builtin_amdgcn_mfma_f32_16x16x32_bf16(a1, wf[0][1], acc[0][rg], 0, 0, 0);
      acc[1][rg] = __builtin_amdgcn_mfma_f32_16x16x32_bf16(a1, wf[1][1], acc[1][rg], 0, 0, 0);
      acc[0][rg] = __builtin_amdgcn_mfma_f32_16x16x32_bf16(a2, wf[0][2], acc[0][rg], 0, 0, 0);
      acc[1][rg] = __builtin_amdgcn_mfma_f32_16x16x32_bf16(a2, wf[1][2], acc[1][rg], 0, 0, 0);
      acc[0][rg] = __builtin_amdgcn_mfma_f32_16x16x32_bf16(a3, wf[0][3], acc[0][rg], 0, 0, 0);
      acc[1][rg] = __builtin_amdgcn_mfma_f32_16x16x32_bf16(a3, wf[1][3], acc[1][rg], 0, 0, 0);
      acc[0][rg] = __builtin_amdgcn_mfma_f32_16x16x32_bf16(a4, wf[0][4], acc[0][rg], 0, 0, 0);
      acc[1][rg] = __builtin_amdgcn_mfma_f32_16x16x32_bf16(a4, wf[1][4], acc[1][rg], 0, 0, 0);
      acc[0][rg] = __builtin_amdgcn_mfma_f32_16x16x32_bf16(a5, wf[0][5], acc[0][rg], 0, 0, 0);
      acc[1][rg] = __builtin_amdgcn_mfma_f32_16x16x32_bf16(a5, wf[1][5], acc[1][rg], 0, 0, 0);
    }

    // stats from registers (D layout: row = rg*16 + lg*4 + r, col = cg*64+colF)
    #pragma unroll
    for (int cg = 0; cg < 2; ++cg) {
      #pragma unroll
      for (int rg = 0; rg < 4; ++rg) {
        float z0 = acc[cg][rg][0], z1 = acc[cg][rg][1];
        float z2 = acc[cg][rg][2], z3 = acc[cg][rg][3];
        fs[cg] += (z0 + z1) + (z2 + z3);
        fq[cg] += z0 * z0 + z1 * z1 + z2 * z2 + z3 * z3;
      }
    }

    __syncthreads();   // [P] prior iteration's Zl row-reads complete

    // transpose: acc -> Zl rows [64][ZLD] fp16
    #pragma unroll
    for (int cg = 0; cg < 2; ++cg)
      #pragma unroll
      for (int rg = 0; rg < 4; ++rg)
        #pragma unroll
        for (int r = 0; r < 4; ++r)
          Zl[(rg * 16 + lg * 4 + r) * ZLD + cg * 64 + colF] = f2h(acc[cg][rg][r]);

    __syncthreads();   // [Q] z rows complete in LDS

    // write row orow (4 threads x 64B = 256B) to its CSR slot
    {
      int pos = iperm[tile * 64 + orow];
      const s16x8* src = (const s16x8*)&Zl[orow * ZLD + oq * 32];
      s16x8 v0 = src[0], v1 = src[1], v2 = src[2], v3 = src[3];
      unsigned short* dst = zc + (size_t)pos * 128 + oq * 32;
      *(s16x8*)dst = v0;
      *(s16x8*)(dst + 8) = v1;
      *(s16x8*)(dst + 16) = v2;
      *(s16x8*)(dst + 24) = v3;
    }
  }

  #pragma unroll
  for (int cg = 0; cg < 2; ++cg) {
    fs[cg] += __shfl_xor(fs[cg], 16, 64); fs[cg] += __shfl_xor(fs[cg], 32, 64);
    fq[cg] += __shfl_xor(fq[cg], 16, 64); fq[cg] += __shfl_xor(fq[cg], 32, 64);
  }
  if (lane < 16) {
    atomicAdd(&stats[colF], fs[0]);
    atomicAdd(&stats[colC], fs[1]);
    atomicAdd(&stats[128 + colF], fq[0]);
    atomicAdd(&stats[128 + colC], fq[1]);
  }
}

// ---------------- BN1 finalize (b_full == 0; bias cancels inside BN anyway) --
__global__ void finalize1_k(const float* __restrict__ stats,
                            const float* __restrict__ g,
                            const float* __restrict__ be,
                            float* __restrict__ ab) {
  int n = threadIdx.x;   // 128
  float mu = stats[n] * (1.f / N_EDGES);
  float var = stats[128 + n] * (1.f / N_EDGES) - mu * mu;
  float a = g[n] * rsqrtf(var + 1e-5f);
  ab[n] = a;
  ab[128 + n] = be[n] - mu * a;
}

// ---------------- gather + gate: one wave per node, contiguous CSR rows ------
__launch_bounds__(256)
__global__ void gather_k(const unsigned short* __restrict__ zc,
                         const int* __restrict__ rowptr,
                         const float* __restrict__ ab,
                         float* __restrict__ out) {
  int n = blockIdx.x * 4 + (threadIdx.x >> 6);
  if (n >= N_NODES) return;
  int c = threadIdx.x & 63;
  float af = ab[c], cf = ab[128 + c];
  float ag = ab[64 + c], cg2 = ab[192 + c];
  int s = rowptr[n], e = rowptr[n + 1];
  float acc = 0.f;
  int i = s;
  for (; i + 2 <= e; i += 2) {               // 2 rows/iter for MLP
    const unsigned short* r0 = zc + (size_t)i * 128;
    const unsigned short* r1 = r0 + 128;
    float f0 = af * h2f(r0[c]) + cf;
    float g0 = ag * h2f(r0[64 + c]) + cg2;
    float f1 = af * h2f(r1[c]) + cf;
    float g1 = ag * h2f(r1[64 + c]) + cg2;
    acc += fast_sigmoid(f0) * fast_softplus(g0);
    acc += fast_sigmoid(f1) * fast_softplus(g1);
  }
  if (i < e) {
    const unsigned short* r0 = zc + (size_t)i * 128;
    float f0 = af * h2f(r0[c]) + cf;
    float g0 = ag * h2f(r0[64 + c]) + cg2;
    acc += fast_sigmoid(f0) * fast_softplus(g0);
  }
  out[(size_t)n * 64 + c] = acc;
}

// ---------------- node-side stats / finalize / output ------------------------
__launch_bounds__(256)
__global__ void stats2_k(const float* __restrict__ upd, float* __restrict__ stats2) {
  int tid = threadIdx.x;
  int gid = blockIdx.x * 256 + tid;
  int stride = gridDim.x * 256;
  float4 s = make_float4(0.f, 0.f, 0.f, 0.f);
  float4 q = make_float4(0.f, 0.f, 0.f, 0.f);
  for (int i = gid; i < N_NODES * 16; i += stride) {
    float4 v = ((const float4*)upd)[i];
    s.x += v.x; s.y += v.y; s.z += v.z; s.w += v.w;
    q.x += v.x * v.x; q.y += v.y * v.y; q.z += v.z * v.z; q.w += v.w * v.w;
  }
  int lane = tid & 63;
  int wv = tid >> 6;
  s.x += __shfl_xor(s.x, 16, 64); s.x += __shfl_xor(s.x, 32, 64);
  s.y += __shfl_xor(s.y, 16, 64); s.y += __shfl_xor(s.y, 32, 64);
  s.z += __shfl_xor(s.z, 16, 64); s.z += __shfl_xor(s.z, 32, 64);
  s.w += __shfl_xor(s.w, 16, 64); s.w += __shfl_xor(s.w, 32, 64);
  q.x += __shfl_xor(q.x, 16, 64); q.x += __shfl_xor(q.x, 32, 64);
  q.y += __shfl_xor(q.y, 16, 64); q.y += __shfl_xor(q.y, 32, 64);
  q.z += __shfl_xor(q.z, 16, 64); q.z += __shfl_xor(q.z, 32, 64);
  q.w += __shfl_xor(q.w, 16, 64); q.w += __shfl_xor(q.w, 32, 64);
  __shared__ float red[4 * 128];
  if (lane < 16) {
    int f = lane * 4;
    red[wv * 128 + f + 0] = s.x; red[wv * 128 + f + 1] = s.y;
    red[wv * 128 + f + 2] = s.z; red[wv * 128 + f + 3] = s.w;
    red[wv * 128 + 64 + f + 0] = q.x; red[wv * 128 + 64 + f + 1] = q.y;
    red[wv * 128 + 64 + f + 2] = q.z; red[wv * 128 + 64 + f + 3] = q.w;
  }
  __syncthreads();
  if (tid < 128) {
    float v = red[tid] + red[128 + tid] + red[256 + tid] + red[384 + tid];
    atomicAdd(&stats2[tid], v);
  }
}

__global__ void finalize2_k(const float* __restrict__ stats2,
                            const float* __restrict__ g,
                            const float* __restrict__ be,
                            float* __restrict__ ab2) {
  int f = threadIdx.x;   // 64
  float mu = stats2[f] * (1.f / N_NODES);
  float var = stats2[64 + f] * (1.f / N_NODES) - mu * mu;
  float a = g[f] * rsqrtf(var + 1e-5f);
  ab2[f] = a;
  ab2[64 + f] = be[f] - mu * a;
}

__launch_bounds__(256)
__global__ void out_k(const float* __restrict__ atom,
                      const float* __restrict__ ab2,
                      float* __restrict__ out) {
  int gid = blockIdx.x * 256 + threadIdx.x;
  int stride = gridDim.x * 256;
  for (int i = gid; i < N_NODES * 16; i += stride) {
    float4 u = ((const float4*)out)[i];
    float4 x = ((const float4*)atom)[i];
    int f = (i & 15) * 4;
    float4 r;
    r.x = softplus_f(x.x + u.x * ab2[f + 0] + ab2[64 + f + 0]);
    r.y = softplus_f(x.y + u.y * ab2[f + 1] + ab2[64 + f + 1]);
    r.z = softplus_f(x.z + u.z * ab2[f + 2] + ab2[64 + f + 2]);
    r.w = softplus_f(x.w + u.w * ab2[f + 3] + ab2[64 + f + 3]);
    ((float4*)out)[i] = r;
  }
}

// ================= FALLBACK (round-1 two-pass path, known-good) ==============
template<int PASS>
__launch_bounds__(256, 2)
__global__ void edge_pass(const float* __restrict__ atom,
                          const float* __restrict__ nbr,
                          const int* __restrict__ esrc,
                          const int* __restrict__ edst,
                          const float* __restrict__ W,
                          const float* __restrict__ bvec,
                          float* __restrict__ stats,
                          const float* __restrict__ ab,
                          float* __restrict__ upd) {
  __shared__ short Wl[DOUT * LDW];
  __shared__ short Tl[EPB * LDW];
  __shared__ int eix[2 * EPB];

  const int tid = threadIdx.x;
  const int lane = tid & 63;
  const int wv = tid >> 6;
  const int l15 = lane & 15;
  const int lg = lane >> 4;

  for (int i = tid; i < DIN * DOUT; i += 256) {
    int k = i >> 7, n = i & 127;
    Wl[n * LDW + k] = f2bf(W[i]);
  }
  float bcol[8], acol[8], ccol[8];
  #pragma unroll
  for (int j = 0; j < 8; ++j) {
    int n = j * 16 + l15;
    bcol[j] = bvec[n];
    if constexpr (PASS == 1) { acol[j] = ab[n]; ccol[j] = ab[DOUT + n]; }
    else { acol[j] = 0.f; ccol[j] = 0.f; }
  }
  float fsum[8], fsq[8];
  #pragma unroll
  for (int j = 0; j < 8; ++j) { fsum[j] = 0.f; fsq[j] = 0.f; }

  for (int tile = blockIdx.x; tile < NTILES; tile += gridDim.x) {
    const int e0 = tile * EPB;
    __syncthreads();
    if (tid < EPB) eix[tid] = esrc[e0 + tid];
    else if (tid < 2 * EPB) eix[tid] = edst[e0 + tid - EPB];
    __syncthreads();
    for (int i = tid; i < EPB * 96; i += 256) {
      int row = i / 96;
      int cl = (i - row * 96) * 2;
      const float* p;
      if (cl < 64)       p = atom + (size_t)eix[row] * 64 + cl;
      else if (cl < 128) p = atom + (size_t)eix[EPB + row] * 64 + (cl - 64);
      else               p = nbr + (size_t)(e0 + row) * 64 + (cl - 128);
      float2 v = *(const float2*)p;
      unsigned pk = (unsigned)(unsigned short)f2bf(v.x)
                  | ((unsigned)(unsigned short)f2bf(v.y) << 16);
      *(unsigned*)&Tl[row * LDW + cl] = pk;
    }
    __syncthreads();
    f32x4 acc[8] = {};
    const int abase = (wv * 16 + l15) * LDW + lg * 8;
    #pragma unroll
    for (int kk = 0; kk < 6; ++kk) {
      bf16x8 afr = *(const bf16x8*)&Tl[abase + kk * 32];
      #pragma unroll
      for (int j = 0; j < 8; ++j) {
        bf16x8 bfr = *(const bf16x8*)&Wl[(j * 16 + l15) * LDW + lg * 8 + kk * 32];
        acc[j] = __builtin_amdgcn_mfma_f32_16x16x32_bf16(afr, bfr, acc[j], 0, 0, 0);
      }
    }
    if constexpr (PASS == 0) {
      #pragma unroll
      for (int j = 0; j < 8; ++j)
        #pragma unroll
        for (int r = 0; r < 4; ++r) {
          float z = acc[j][r] + bcol[j];
          fsum[j] += z; fsq[j] += z * z;
        }
    } else {
      #pragma unroll
      for (int r = 0; r < 4; ++r) {
        int row = wv * 16 + lg * 4 + r;
        int d = eix[EPB + row];
        float* urow = upd + (size_t)d * 64;
        #pragma unroll
        for (int j = 0; j < 4; ++j) {
          float f = (acc[j][r] + bcol[j]) * acol[j] + ccol[j];
          float g = (acc[j + 4][r] + bcol[j + 4]) * acol[j + 4] + ccol[j + 4];
          atomicAdd(&urow[j * 16 + l15], sigmoid_f(f) * softplus_f(g));
        }
      }
    }
  }
  if constexpr (PASS == 0) {
    #pragma unroll
    for (int j = 0; j < 8; ++j) {
      fsum[j] += __shfl_xor(fsum[j], 16, 64);
      fsum[j] += __shfl_xor(fsum[j], 32, 64);
      fsq[j]  += __shfl_xor(fsq[j], 16, 64);
      fsq[j]  += __shfl_xor(fsq[j], 32, 64);
    }
    __syncthreads();
    float* redf = (float*)Tl;
    if (lane < 16) {
      #pragma unroll
      for (int j = 0; j < 8; ++j) {
        redf[wv * 256 + j * 16 + lane] = fsum[j];
        redf[wv * 256 + 128 + j * 16 + lane] = fsq[j];
      }
    }
    __syncthreads();
    float s = redf[tid] + redf[256 + tid] + redf[512 + tid] + redf[768 + tid];
    atomicAdd(&stats[tid], s);
  }
}

// =============================================================================
extern "C" void kernel_launch(void* const* d_in, const int* in_sizes, int n_in,
                              void* d_out, int out_size, void* d_ws, size_t ws_size,
                              hipStream_t stream) {
  const float* atom = (const float*)d_in[0];
  const float* nbr  = (const float*)d_in[1];
  const int*   esrc = (const int*)d_in[2];
  const int*   edst = (const int*)d_in[3];
  const float* W    = (const float*)d_in[4];
  const float* bvec = (const float*)d_in[5];
  const float* g1   = (const float*)d_in[6];
  const float* b1   = (const float*)d_in[7];
  const float* g2   = (const float*)d_in[8];
  const float* b2   = (const float*)d_in[9];
  float* out = (float*)d_out;
  char* ws = (char*)d_ws;

  float* stats1 = (float*)ws;          // [256]
  float* ab1    = stats1 + 256;        // [256]
  float* stats2 = stats1 + 512;        // [128]
  float* ab2    = stats1 + 640;        // [128]

  const size_t OFF_ATOM = 4096;
  const size_t SZ_ATOM  = (size_t)N_NODES * ATOMF * 2;    //   6.4 MB
  const size_t OFF_NBR  = OFF_ATOM + SZ_ATOM;
  const size_t SZ_NBR   = (size_t)N_EDGES * ATOMF * 2;    // 102.4 MB
  const size_t OFF_ZT   = OFF_NBR + SZ_NBR;
  const size_t SZ_ZT    = (size_t)N_EDGES * DOUT * 2;     // 204.8 MB (z_csr)
  const size_t OFF_PERM = OFF_ZT + SZ_ZT;
  const size_t SZ_PERM  = (size_t)N_EDGES * 4;            //   3.2 MB
  const size_t OFF_DEG  = OFF_PERM + SZ_PERM;
  const size_t OFF_RP   = OFF_DEG + N_NODES * 4;
  const size_t OFF_CUR  = OFF_RP + (N_NODES + 1) * 4 + 12;   // keep 16B align
  const size_t NEED_NEW = OFF_CUR + N_NODES * 4;          // ~317.8 MB

  hipMemsetAsync(stats1, 0, 768 * sizeof(float), stream);

  if (ws_size >= NEED_NEW) {
    unsigned short* atom_bf = (unsigned short*)(ws + OFF_ATOM);
    unsigned short* nbr_bf  = (unsigned short*)(ws + OFF_NBR);
    unsigned short* zc      = (unsigned short*)(ws + OFF_ZT);
    int* iperm  = (int*)(ws + OFF_PERM);
    int* deg    = (int*)(ws + OFF_DEG);
    int* rowptr = (int*)(ws + OFF_RP);
    int* cursor = (int*)(ws + OFF_CUR);

    hipMemsetAsync(deg, 0, N_NODES * sizeof(int), stream);
    precvt_k<<<2048, 256, 0, stream>>>(atom, nbr, edst, atom_bf, nbr_bf, deg);
    scan_k<<<1, 1024, 0, stream>>>(deg, rowptr, cursor);
    fill_k<<<(N_EDGES + 255) / 256, 256, 0, stream>>>(edst, cursor, iperm);

    edge_gemm<<<1536, 256, 0, stream>>>(atom_bf, nbr_bf, esrc, edst, iperm,
                                        W, stats1, zc);
    finalize1_k<<<1, 128, 0, stream>>>(stats1, g1, b1, ab1);

    gather_k<<<(N_NODES + 3) / 4, 256, 0, stream>>>(zc, rowptr, ab1, out);
  } else {
    hipMemsetAsync(out, 0, (size_t)N_NODES * 64 * sizeof(float), stream);
    edge_pass<0><<<512, 256, 0, stream>>>(atom, nbr, esrc, edst, W, bvec,
                                          stats1, nullptr, nullptr);
    finalize1_k<<<1, 128, 0, stream>>>(stats1, g1, b1, ab1);
    edge_pass<1><<<512, 256, 0, stream>>>(atom, nbr, esrc, edst, W, bvec,
                                          nullptr, ab1, out);
  }

  stats2_k<<<512, 256, 0, stream>>>(out, stats2);
  finalize2_k<<<1, 64, 0, stream>>>(stats2, g2, b2, ab2);
  out_k<<<512, 256, 0, stream>>>(atom, ab2, out);
}

// Round 14
// 444.411 us; speedup vs baseline: 1.1779x; 1.1779x over previous
//
#include <hip/hip_runtime.h>
#include <hip/hip_fp16.h>
#include <math.h>

#define N_NODES 50000
#define N_EDGES 800000
#define ATOMF 64
#define DIN 192
#define DOUT 128
#define EPB 64
#define NTILES (N_EDGES / EPB)   // 12500
#define LDW 200                  // fallback LDS stride
#define ZLD 136                  // z-LDS row stride in fp16 (272B, 16B-aligned rows)

typedef __attribute__((ext_vector_type(8))) short bf16x8;
typedef __attribute__((ext_vector_type(8))) short s16x8;
typedef __attribute__((ext_vector_type(4))) float f32x4;

__device__ __forceinline__ short f2bf(float f) {
  unsigned u = __float_as_uint(f);
  u += 0x7fffu + ((u >> 16) & 1u);   // RNE
  return (short)(u >> 16);
}
__device__ __forceinline__ unsigned short f2h(float f) {
  __half h = __float2half_rn(f);     // v_cvt_f16_f32 (RNE)
  return *(unsigned short*)&h;
}
__device__ __forceinline__ float h2f(unsigned short u) {
  __half h = *(__half*)&u;
  return __half2float(h);            // v_cvt_f32_f16
}
__device__ __forceinline__ float softplus_f(float x) {
  return fmaxf(x, 0.f) + log1pf(__expf(-fabsf(x)));
}
__device__ __forceinline__ float sigmoid_f(float x) {
  return 1.f / (1.f + __expf(-x));
}
// fast variants for the 51.2M-element gate (err ~1e-6, threshold 0.24)
__device__ __forceinline__ float fast_sigmoid(float x) {
  return __builtin_amdgcn_rcpf(1.f + __expf(-x));
}
__device__ __forceinline__ float fast_softplus(float x) {
  return fmaxf(x, 0.f) + __logf(1.f + __expf(-fabsf(x)));
}

// ---------------- fp32 -> bf16 pre-convert (ATOM ONLY) + degree histogram ----
__launch_bounds__(256)
__global__ void precvt_k(const float* __restrict__ atom,
                         const int* __restrict__ edst,
                         unsigned short* __restrict__ atom_bf,
                         int* __restrict__ deg) {
  const int NA = N_NODES * ATOMF / 8;        // 400000 chunks of 8
  int gid = blockIdx.x * blockDim.x + threadIdx.x;
  int stride = gridDim.x * blockDim.x;
  for (int i = gid; i < N_EDGES; i += stride) atomicAdd(&deg[edst[i]], 1);
  for (int i = gid; i < NA; i += stride) {
    const float* s = atom + (size_t)i * 8;
    float4 a = ((const float4*)s)[0];
    float4 b = ((const float4*)s)[1];
    s16x8 t;
    t[0] = f2bf(a.x); t[1] = f2bf(a.y); t[2] = f2bf(a.z); t[3] = f2bf(a.w);
    t[4] = f2bf(b.x); t[5] = f2bf(b.y); t[6] = f2bf(b.z); t[7] = f2bf(b.w);
    *(s16x8*)(atom_bf + (size_t)i * 8) = t;
  }
}

// ---------------- CSR build: scan (x4 vectorized) -> fill (inverse perm) -----
__launch_bounds__(1024)
__global__ void scan_k(const int* __restrict__ deg,
                       int* __restrict__ rowptr,
                       int* __restrict__ cursor) {
  __shared__ int wsum[16];
  const int tid = threadIdx.x;
  const int lane = tid & 63, wv = tid >> 6;
  const int N4 = N_NODES / 4;                // 12500 int4 chunks
  int base = 0;
  for (int c0 = 0; c0 < N4; c0 += 1024) {
    int i4 = c0 + tid;
    int4 v = make_int4(0, 0, 0, 0);
    if (i4 < N4) v = ((const int4*)deg)[i4];
    int t = v.x + v.y + v.z + v.w;
    int s = t;
    #pragma unroll
    for (int d = 1; d < 64; d <<= 1) {
      int u = __shfl_up(s, d, 64);
      if (lane >= d) s += u;
    }
    if (lane == 63) wsum[wv] = s;
    __syncthreads();
    if (wv == 0 && lane < 16) {
      int ws = wsum[lane];
      #pragma unroll
      for (int d = 1; d < 16; d <<= 1) {
        int u = __shfl_up(ws, d, 64);
        if (lane >= d) ws += u;
      }
      wsum[lane] = ws;
    }
    __syncthreads();
    int wbase = wv ? wsum[wv - 1] : 0;
    int excl = base + wbase + s - t;         // exclusive prefix for 4-chunk
    if (i4 < N4) {
      int4 r;
      r.x = excl;
      r.y = excl + v.x;
      r.z = r.y + v.y;
      r.w = r.z + v.z;
      ((int4*)rowptr)[i4] = r;
      ((int4*)cursor)[i4] = r;
    }
    int tot = wsum[15];
    __syncthreads();   // everyone done reading wsum before next iter overwrites
    base += tot;
  }
  if (tid == 0) rowptr[N_NODES] = base;      // == N_EDGES
}

__launch_bounds__(256)
__global__ void fill_k(const int* __restrict__ edst,
                       int* __restrict__ cursor,
                       int* __restrict__ iperm) {
  int gid = blockIdx.x * 256 + threadIdx.x;
  if (gid < N_EDGES) {
    int pos = atomicAdd(&cursor[edst[gid]], 1);
    iperm[gid] = pos;          // inverse perm: edge -> CSR slot
  }
}

// ---------------- edge pass: DIRECT-LOAD fragments -> MFMA -> z rows ---------
// No LDS staging: each lane loads its 16B (atom, bf16) / 32B (nbr, fp32)
// A-fragment straight from global. Register-dest loads => normal compiler
// waitcnt/scheduling. LDS only for the z transpose (2 barriers/tile).
// PROVEN config: (256,4) + grid 1024. (256,6) caps VGPR at 40 -> ~1GB spill
// traffic (rounds 7 & 13). Do not raise the occupancy bound on this kernel.
// z_csr layout: zc[pos][128] fp16, row-major, pos = CSR slot of the edge.
__launch_bounds__(256, 4)
__global__ void edge_gemm(const unsigned short* __restrict__ atom_bf,
                          const float* __restrict__ nbr,
                          const int* __restrict__ esrc,
                          const int* __restrict__ edst,
                          const int* __restrict__ iperm,
                          const float* __restrict__ W,
                          float* __restrict__ stats,
                          unsigned short* __restrict__ zc) {
  __shared__ unsigned short Zl[EPB * ZLD];   // 17408 B (z transpose only)

  const int tid = threadIdx.x;
  const int lane = tid & 63;
  const int wv = tid >> 6;
  const int l15 = lane & 15;
  const int lg = lane >> 4;
  const int colF = wv * 16 + l15;            // filter column
  const int colC = colF + 64;                // core column

  // W fragments in registers: wf[cg][kk][jj] = W[kk*32+lg*8+jj][cg*64+colF]
  bf16x8 wf[2][6];
  #pragma unroll
  for (int cg = 0; cg < 2; ++cg) {
    #pragma unroll
    for (int kk = 0; kk < 6; ++kk) {
      bf16x8 t;
      #pragma unroll
      for (int jj = 0; jj < 8; ++jj)
        t[jj] = f2bf(W[(size_t)(kk * 32 + lg * 8 + jj) * 128 + cg * 64 + colF]);
      wf[cg][kk] = t;
    }
  }

  const int orow = tid >> 2;                 // output row 0..63
  const int oq = tid & 3;                    // 32-col chunk 0..3

  float fs[2] = {0.f, 0.f}, fq[2] = {0.f, 0.f};

  for (int tile = blockIdx.x; tile < NTILES; tile += gridDim.x) {
    const int e0 = tile * EPB;

    f32x4 acc[2][4] = {};
    #pragma unroll
    for (int rg = 0; rg < 4; ++rg) {
      int e = e0 + rg * 16 + l15;            // this lane's edge row
      const unsigned short* srcb = atom_bf + (size_t)esrc[e] * ATOMF + lg * 8;
      const unsigned short* dstb = atom_bf + (size_t)edst[e] * ATOMF + lg * 8;
      const float* nbf = nbr + (size_t)e * ATOMF + lg * 8;
      bf16x8 a0 = *(const bf16x8*)srcb;        // cols   0.. 31 slice
      bf16x8 a1 = *(const bf16x8*)(srcb + 32); // cols  32.. 63
      bf16x8 a2 = *(const bf16x8*)dstb;        // cols  64.. 95
      bf16x8 a3 = *(const bf16x8*)(dstb + 32); // cols  96..127
      float4 n0 = ((const float4*)nbf)[0];     // nbr fp32, convert in-register
      float4 n1 = ((const float4*)nbf)[1];
      float4 n2 = ((const float4*)(nbf + 32))[0];
      float4 n3 = ((const float4*)(nbf + 32))[1];
      bf16x8 a4, a5;
      a4[0] = f2bf(n0.x); a4[1] = f2bf(n0.y); a4[2] = f2bf(n0.z); a4[3] = f2bf(n0.w);
      a4[4] = f2bf(n1.x); a4[5] = f2bf(n1.y); a4[6] = f2bf(n1.z); a4[7] = f2bf(n1.w);
      a5[0] = f2bf(n2.x); a5[1] = f2bf(n2.y); a5[2] = f2bf(n2.z); a5[3] = f2bf(n2.w);
      a5[4] = f2bf(n3.x); a5[5] = f2bf(n3.y); a5[6] = f2bf(n3.z); a5[7] = f2bf(n3.w);
      acc[0][rg] = __builtin_amdgcn_mfma_f32_16x16x32_bf16(a0, wf[0][0], acc[0][rg], 0, 0, 0);
      acc[1][rg] = __builtin_amdgcn_mfma_f32_16x16x32_bf16(a0, wf[1][0], acc[1][rg], 0, 0, 0);
      acc[0][rg] = __builtin_amdgcn_mfma_f32_16x16x32_bf16(a1, wf[0][1], acc[0][rg], 0, 0, 0);
      acc[1][rg] = __builtin_amdgcn_mfma_f32_16x16x32_bf16(a1, wf[1][1], acc[1][rg], 0, 0, 0);
      acc[0][rg] = __builtin_amdgcn_mfma_f32_16x16x32_bf16(a2, wf[0][2], acc[0][rg], 0, 0, 0);
      acc[1][rg] = __builtin_amdgcn_mfma_f32_16x16x32_bf16(a2, wf[1][2], acc[1][rg], 0, 0, 0);
      acc[0][rg] = __builtin_amdgcn_mfma_f32_16x16x32_bf16(a3, wf[0][3], acc[0][rg], 0, 0, 0);
      acc[1][rg] = __builtin_amdgcn_mfma_f32_16x16x32_bf16(a3, wf[1][3], acc[1][rg], 0, 0, 0);
      acc[0][rg] = __builtin_amdgcn_mfma_f32_16x16x32_bf16(a4, wf[0][4], acc[0][rg], 0, 0, 0);
      acc[1][rg] = __builtin_amdgcn_mfma_f32_16x16x32_bf16(a4, wf[1][4], acc[1][rg], 0, 0, 0);
      acc[0][rg] = __builtin_amdgcn_mfma_f32_16x16x32_bf16(a5, wf[0][5], acc[0][rg], 0, 0, 0);
      acc[1][rg] = __builtin_amdgcn_mfma_f32_16x16x32_bf16(a5, wf[1][5], acc[1][rg], 0, 0, 0);
    }

    // stats from registers (D layout: row = rg*16 + lg*4 + r, col = cg*64+colF)
    #pragma unroll
    for (int cg = 0; cg < 2; ++cg) {
      #pragma unroll
      for (int rg = 0; rg < 4; ++rg) {
        float z0 = acc[cg][rg][0], z1 = acc[cg][rg][1];
        float z2 = acc[cg][rg][2], z3 = acc[cg][rg][3];
        fs[cg] += (z0 + z1) + (z2 + z3);
        fq[cg] += z0 * z0 + z1 * z1 + z2 * z2 + z3 * z3;
      }
    }

    __syncthreads();   // [P] prior iteration's Zl row-reads complete

    // transpose: acc -> Zl rows [64][ZLD] fp16
    #pragma unroll
    for (int cg = 0; cg < 2; ++cg)
      #pragma unroll
      for (int rg = 0; rg < 4; ++rg)
        #pragma unroll
        for (int r = 0; r < 4; ++r)
          Zl[(rg * 16 + lg * 4 + r) * ZLD + cg * 64 + colF] = f2h(acc[cg][rg][r]);

    __syncthreads();   // [Q] z rows complete in LDS

    // write row orow (4 threads x 64B = 256B) to its CSR slot
    {
      int pos = iperm[tile * 64 + orow];
      const s16x8* src = (const s16x8*)&Zl[orow * ZLD + oq * 32];
      s16x8 v0 = src[0], v1 = src[1], v2 = src[2], v3 = src[3];
      unsigned short* dst = zc + (size_t)pos * 128 + oq * 32;
      *(s16x8*)dst = v0;
      *(s16x8*)(dst + 8) = v1;
      *(s16x8*)(dst + 16) = v2;
      *(s16x8*)(dst + 24) = v3;
    }
  }

  #pragma unroll
  for (int cg = 0; cg < 2; ++cg) {
    fs[cg] += __shfl_xor(fs[cg], 16, 64); fs[cg] += __shfl_xor(fs[cg], 32, 64);
    fq[cg] += __shfl_xor(fq[cg], 16, 64); fq[cg] += __shfl_xor(fq[cg], 32, 64);
  }
  if (lane < 16) {
    atomicAdd(&stats[colF], fs[0]);
    atomicAdd(&stats[colC], fs[1]);
    atomicAdd(&stats[128 + colF], fq[0]);
    atomicAdd(&stats[128 + colC], fq[1]);
  }
}

// ---------------- BN1 finalize (b_full == 0; bias cancels inside BN anyway) --
__global__ void finalize1_k(const float* __restrict__ stats,
                            const float* __restrict__ g,
                            const float* __restrict__ be,
                            float* __restrict__ ab) {
  int n = threadIdx.x;   // 128
  float mu = stats[n] * (1.f / N_EDGES);
  float var = stats[128 + n] * (1.f / N_EDGES) - mu * mu;
  float a = g[n] * rsqrtf(var + 1e-5f);
  ab[n] = a;
  ab[128 + n] = be[n] - mu * a;
}

// ---------------- gather + gate: one wave per node, contiguous CSR rows ------
__launch_bounds__(256)
__global__ void gather_k(const unsigned short* __restrict__ zc,
                         const int* __restrict__ rowptr,
                         const float* __restrict__ ab,
                         float* __restrict__ out) {
  int n = blockIdx.x * 4 + (threadIdx.x >> 6);
  if (n >= N_NODES) return;
  int c = threadIdx.x & 63;
  float af = ab[c], cf = ab[128 + c];
  float ag = ab[64 + c], cg2 = ab[192 + c];
  int s = rowptr[n], e = rowptr[n + 1];
  float acc = 0.f;
  int i = s;
  for (; i + 2 <= e; i += 2) {               // 2 rows/iter for MLP
    const unsigned short* r0 = zc + (size_t)i * 128;
    const unsigned short* r1 = r0 + 128;
    float f0 = af * h2f(r0[c]) + cf;
    float g0 = ag * h2f(r0[64 + c]) + cg2;
    float f1 = af * h2f(r1[c]) + cf;
    float g1 = ag * h2f(r1[64 + c]) + cg2;
    acc += fast_sigmoid(f0) * fast_softplus(g0);
    acc += fast_sigmoid(f1) * fast_softplus(g1);
  }
  if (i < e) {
    const unsigned short* r0 = zc + (size_t)i * 128;
    float f0 = af * h2f(r0[c]) + cf;
    float g0 = ag * h2f(r0[64 + c]) + cg2;
    acc += fast_sigmoid(f0) * fast_softplus(g0);
  }
  out[(size_t)n * 64 + c] = acc;
}

// ---------------- node-side stats / finalize / output ------------------------
__launch_bounds__(256)
__global__ void stats2_k(const float* __restrict__ upd, float* __restrict__ stats2) {
  int tid = threadIdx.x;
  int gid = blockIdx.x * 256 + tid;
  int stride = gridDim.x * 256;
  float4 s = make_float4(0.f, 0.f, 0.f, 0.f);
  float4 q = make_float4(0.f, 0.f, 0.f, 0.f);
  for (int i = gid; i < N_NODES * 16; i += stride) {
    float4 v = ((const float4*)upd)[i];
    s.x += v.x; s.y += v.y; s.z += v.z; s.w += v.w;
    q.x += v.x * v.x; q.y += v.y * v.y; q.z += v.z * v.z; q.w += v.w * v.w;
  }
  int lane = tid & 63;
  int wv = tid >> 6;
  s.x += __shfl_xor(s.x, 16, 64); s.x += __shfl_xor(s.x, 32, 64);
  s.y += __shfl_xor(s.y, 16, 64); s.y += __shfl_xor(s.y, 32, 64);
  s.z += __shfl_xor(s.z, 16, 64); s.z += __shfl_xor(s.z, 32, 64);
  s.w += __shfl_xor(s.w, 16, 64); s.w += __shfl_xor(s.w, 32, 64);
  q.x += __shfl_xor(q.x, 16, 64); q.x += __shfl_xor(q.x, 32, 64);
  q.y += __shfl_xor(q.y, 16, 64); q.y += __shfl_xor(q.y, 32, 64);
  q.z += __shfl_xor(q.z, 16, 64); q.z += __shfl_xor(q.z, 32, 64);
  q.w += __shfl_xor(q.w, 16, 64); q.w += __shfl_xor(q.w, 32, 64);
  __shared__ float red[4 * 128];
  if (lane < 16) {
    int f = lane * 4;
    red[wv * 128 + f + 0] = s.x; red[wv * 128 + f + 1] = s.y;
    red[wv * 128 + f + 2] = s.z; red[wv * 128 + f + 3] = s.w;
    red[wv * 128 + 64 + f + 0] = q.x; red[wv * 128 + 64 + f + 1] = q.y;
    red[wv * 128 + 64 + f + 2] = q.z; red[wv * 128 + 64 + f + 3] = q.w;
  }
  __syncthreads();
  if (tid < 128) {
    float v = red[tid] + red[128 + tid] + red[256 + tid] + red[384 + tid];
    atomicAdd(&stats2[tid], v);
  }
}

__global__ void finalize2_k(const float* __restrict__ stats2,
                            const float* __restrict__ g,
                            const float* __restrict__ be,
                            float* __restrict__ ab2) {
  int f = threadIdx.x;   // 64
  float mu = stats2[f] * (1.f / N_NODES);
  float var = stats2[64 + f] * (1.f / N_NODES) - mu * mu;
  float a = g[f] * rsqrtf(var + 1e-5f);
  ab2[f] = a;
  ab2[64 + f] = be[f] - mu * a;
}

__launch_bounds__(256)
__global__ void out_k(const float* __restrict__ atom,
                      const float* __restrict__ ab2,
                      float* __restrict__ out) {
  int gid = blockIdx.x * 256 + threadIdx.x;
  int stride = gridDim.x * 256;
  for (int i = gid; i < N_NODES * 16; i += stride) {
    float4 u = ((const float4*)out)[i];
    float4 x = ((const float4*)atom)[i];
    int f = (i & 15) * 4;
    float4 r;
    r.x = softplus_f(x.x + u.x * ab2[f + 0] + ab2[64 + f + 0]);
    r.y = softplus_f(x.y + u.y * ab2[f + 1] + ab2[64 + f + 1]);
    r.z = softplus_f(x.z + u.z * ab2[f + 2] + ab2[64 + f + 2]);
    r.w = softplus_f(x.w + u.w * ab2[f + 3] + ab2[64 + f + 3]);
    ((float4*)out)[i] = r;
  }
}

// ================= FALLBACK (round-1 two-pass path, known-good) ==============
template<int PASS>
__launch_bounds__(256, 2)
__global__ void edge_pass(const float* __restrict__ atom,
                          const float* __restrict__ nbr,
                          const int* __restrict__ esrc,
                          const int* __restrict__ edst,
                          const float* __restrict__ W,
                          const float* __restrict__ bvec,
                          float* __restrict__ stats,
                          const float* __restrict__ ab,
                          float* __restrict__ upd) {
  __shared__ short Wl[DOUT * LDW];
  __shared__ short Tl[EPB * LDW];
  __shared__ int eix[2 * EPB];

  const int tid = threadIdx.x;
  const int lane = tid & 63;
  const int wv = tid >> 6;
  const int l15 = lane & 15;
  const int lg = lane >> 4;

  for (int i = tid; i < DIN * DOUT; i += 256) {
    int k = i >> 7, n = i & 127;
    Wl[n * LDW + k] = f2bf(W[i]);
  }
  float bcol[8], acol[8], ccol[8];
  #pragma unroll
  for (int j = 0; j < 8; ++j) {
    int n = j * 16 + l15;
    bcol[j] = bvec[n];
    if constexpr (PASS == 1) { acol[j] = ab[n]; ccol[j] = ab[DOUT + n]; }
    else { acol[j] = 0.f; ccol[j] = 0.f; }
  }
  float fsum[8], fsq[8];
  #pragma unroll
  for (int j = 0; j < 8; ++j) { fsum[j] = 0.f; fsq[j] = 0.f; }

  for (int tile = blockIdx.x; tile < NTILES; tile += gridDim.x) {
    const int e0 = tile * EPB;
    __syncthreads();
    if (tid < EPB) eix[tid] = esrc[e0 + tid];
    else if (tid < 2 * EPB) eix[tid] = edst[e0 + tid - EPB];
    __syncthreads();
    for (int i = tid; i < EPB * 96; i += 256) {
      int row = i / 96;
      int cl = (i - row * 96) * 2;
      const float* p;
      if (cl < 64)       p = atom + (size_t)eix[row] * 64 + cl;
      else if (cl < 128) p = atom + (size_t)eix[EPB + row] * 64 + (cl - 64);
      else               p = nbr + (size_t)(e0 + row) * 64 + (cl - 128);
      float2 v = *(const float2*)p;
      unsigned pk = (unsigned)(unsigned short)f2bf(v.x)
                  | ((unsigned)(unsigned short)f2bf(v.y) << 16);
      *(unsigned*)&Tl[row * LDW + cl] = pk;
    }
    __syncthreads();
    f32x4 acc[8] = {};
    const int abase = (wv * 16 + l15) * LDW + lg * 8;
    #pragma unroll
    for (int kk = 0; kk < 6; ++kk) {
      bf16x8 afr = *(const bf16x8*)&Tl[abase + kk * 32];
      #pragma unroll
      for (int j = 0; j < 8; ++j) {
        bf16x8 bfr = *(const bf16x8*)&Wl[(j * 16 + l15) * LDW + lg * 8 + kk * 32];
        acc[j] = __builtin_amdgcn_mfma_f32_16x16x32_bf16(afr, bfr, acc[j], 0, 0, 0);
      }
    }
    if constexpr (PASS == 0) {
      #pragma unroll
      for (int j = 0; j < 8; ++j)
        #pragma unroll
        for (int r = 0; r < 4; ++r) {
          float z = acc[j][r] + bcol[j];
          fsum[j] += z; fsq[j] += z * z;
        }
    } else {
      #pragma unroll
      for (int r = 0; r < 4; ++r) {
        int row = wv * 16 + lg * 4 + r;
        int d = eix[EPB + row];
        float* urow = upd + (size_t)d * 64;
        #pragma unroll
        for (int j = 0; j < 4; ++j) {
          float f = (acc[j][r] + bcol[j]) * acol[j] + ccol[j];
          float g = (acc[j + 4][r] + bcol[j + 4]) * acol[j + 4] + ccol[j + 4];
          atomicAdd(&urow[j * 16 + l15], sigmoid_f(f) * softplus_f(g));
        }
      }
    }
  }
  if constexpr (PASS == 0) {
    #pragma unroll
    for (int j = 0; j < 8; ++j) {
      fsum[j] += __shfl_xor(fsum[j], 16, 64);
      fsum[j] += __shfl_xor(fsum[j], 32, 64);
      fsq[j]  += __shfl_xor(fsq[j], 16, 64);
      fsq[j]  += __shfl_xor(fsq[j], 32, 64);
    }
    __syncthreads();
    float* redf = (float*)Tl;
    if (lane < 16) {
      #pragma unroll
      for (int j = 0; j < 8; ++j) {
        redf[wv * 256 + j * 16 + lane] = fsum[j];
        redf[wv * 256 + 128 + j * 16 + lane] = fsq[j];
      }
    }
    __syncthreads();
    float s = redf[tid] + redf[256 + tid] + redf[512 + tid] + redf[768 + tid];
    atomicAdd(&stats[tid], s);
  }
}

// =============================================================================
extern "C" void kernel_launch(void* const* d_in, const int* in_sizes, int n_in,
                              void* d_out, int out_size, void* d_ws, size_t ws_size,
                              hipStream_t stream) {
  const float* atom = (const float*)d_in[0];
  const float* nbr  = (const float*)d_in[1];
  const int*   esrc = (const int*)d_in[2];
  const int*   edst = (const int*)d_in[3];
  const float* W    = (const float*)d_in[4];
  const float* bvec = (const float*)d_in[5];
  const float* g1   = (const float*)d_in[6];
  const float* b1   = (const float*)d_in[7];
  const float* g2   = (const float*)d_in[8];
  const float* b2   = (const float*)d_in[9];
  float* out = (float*)d_out;
  char* ws = (char*)d_ws;

  float* stats1 = (float*)ws;          // [256]
  float* ab1    = stats1 + 256;        // [256]
  float* stats2 = stats1 + 512;        // [128]
  float* ab2    = stats1 + 640;        // [128]

  const size_t OFF_ATOM = 4096;
  const size_t SZ_ATOM  = (size_t)N_NODES * ATOMF * 2;    //   6.4 MB
  const size_t OFF_NBR  = OFF_ATOM + SZ_ATOM;             // (unused now)
  const size_t SZ_NBR   = (size_t)N_EDGES * ATOMF * 2;    // 102.4 MB
  const size_t OFF_ZT   = OFF_NBR + SZ_NBR;
  const size_t SZ_ZT    = (size_t)N_EDGES * DOUT * 2;     // 204.8 MB (z_csr)
  const size_t OFF_PERM = OFF_ZT + SZ_ZT;
  const size_t SZ_PERM  = (size_t)N_EDGES * 4;            //   3.2 MB
  const size_t OFF_DEG  = OFF_PERM + SZ_PERM;
  const size_t OFF_RP   = OFF_DEG + N_NODES * 4;
  const size_t OFF_CUR  = OFF_RP + (N_NODES + 1) * 4 + 12;   // keep 16B align
  const size_t NEED_NEW = OFF_CUR + N_NODES * 4;          // ~317.8 MB

  hipMemsetAsync(stats1, 0, 768 * sizeof(float), stream);

  if (ws_size >= NEED_NEW) {
    unsigned short* atom_bf = (unsigned short*)(ws + OFF_ATOM);
    unsigned short* zc      = (unsigned short*)(ws + OFF_ZT);
    int* iperm  = (int*)(ws + OFF_PERM);
    int* deg    = (int*)(ws + OFF_DEG);
    int* rowptr = (int*)(ws + OFF_RP);
    int* cursor = (int*)(ws + OFF_CUR);

    hipMemsetAsync(deg, 0, N_NODES * sizeof(int), stream);
    precvt_k<<<1024, 256, 0, stream>>>(atom, edst, atom_bf, deg);
    scan_k<<<1, 1024, 0, stream>>>(deg, rowptr, cursor);
    fill_k<<<(N_EDGES + 255) / 256, 256, 0, stream>>>(edst, cursor, iperm);

    edge_gemm<<<1024, 256, 0, stream>>>(atom_bf, nbr, esrc, edst, iperm,
                                        W, stats1, zc);
    finalize1_k<<<1, 128, 0, stream>>>(stats1, g1, b1, ab1);

    gather_k<<<(N_NODES + 3) / 4, 256, 0, stream>>>(zc, rowptr, ab1, out);
  } else {
    hipMemsetAsync(out, 0, (size_t)N_NODES * 64 * sizeof(float), stream);
    edge_pass<0><<<512, 256, 0, stream>>>(atom, nbr, esrc, edst, W, bvec,
                                          stats1, nullptr, nullptr);
    finalize1_k<<<1, 128, 0, stream>>>(stats1, g1, b1, ab1);
    edge_pass<1><<<512, 256, 0, stream>>>(atom, nbr, esrc, edst, W, bvec,
                                          nullptr, ab1, out);
  }

  stats2_k<<<512, 256, 0, stream>>>(out, stats2);
  finalize2_k<<<1, 64, 0, stream>>>(stats2, g2, b2, ab2);
  out_k<<<512, 256, 0, stream>>>(atom, ab2, out);
}